// Round 14
// baseline (416.255 us; speedup 1.0000x reference)
//
#include <hip/hip_runtime.h>
#include <math.h>
#include <stdint.h>

#define N_ROWS 131072
#define DIM 64
#define KC 64
#define NBLK 512
#define ROWS_PB 256

typedef __attribute__((ext_vector_type(8))) short short8;
typedef __attribute__((ext_vector_type(8))) unsigned short ushort8;
typedef __attribute__((ext_vector_type(16))) float float16;
typedef __attribute__((ext_vector_type(4))) unsigned int uint4v;
typedef __attribute__((ext_vector_type(2))) unsigned long long ulong2v;

// scratch layout (float offsets into d_out's compressed region [0, 8388608)):
// WT bf16 [64][131072] = 16.7MB at byte 0; partial [512][64][64] f32 = 8.4MB;
// sumA [512][64]; newC [64][64]; normpart 512 doubles.
// cur aliases clusters_out (ob+8388608).
// attn region untouched until iter 9; compress overwrites compressed last.
#define PARTIAL_OFF 4194304u
#define SUMA_OFF    6291456u
#define NEWC_OFF    6324224u
#define NORM_BYTE_OFF (6328320ull * 4ull)

// round-to-nearest-even bf16 (unbiased; truncation measured 7e-4 cluster err)
__device__ __forceinline__ uint32_t rne16(float a) {
  uint32_t u = __float_as_uint(a);
  return (u + 0x7fffu + ((u >> 16) & 1u)) >> 16;
}

__device__ __forceinline__ uint32_t pack_bf16(float a, float b) {
  return rne16(a) | (rne16(b) << 16);
}

// RNE split: x = hi + lo + eps, |lo| <= 2^-9|x|, |eps| <= 2^-17|x|, unbiased
__device__ __forceinline__ void split2(float a, float b, uint32_t& hi, uint32_t& lo) {
  uint32_t ha = rne16(a), hb = rne16(b);
  hi = ha | (hb << 16);
  float la = a - __uint_as_float(ha << 16);
  float lb = b - __uint_as_float(hb << 16);
  lo = pack_bf16(la, lb);
}

// prep: WT[d][n] = bf16_rne(W[n][d]) (transposed copy for phase-2 B-frags;
// L3-resident 16.7MB, read each iter). Removing WTsh from dkm LDS takes the
// block from ~53KB->35.6KB LDS => 4 blocks/CU (occupancy was the limiter).
__global__ __launch_bounds__(256) void prep_kernel(const float* __restrict__ W,
                                                   unsigned short* __restrict__ WT) {
  __shared__ unsigned short Tsh[64][256];
  const int t = threadIdx.x;
  const int blk = blockIdx.x;
  const int r = blk * 256 + t;
  const float4* p = (const float4*)(W + (size_t)r * DIM);
#pragma unroll
  for (int c = 0; c < 16; ++c) {
    float4 v = p[c];
    Tsh[c * 4 + 0][t] = (unsigned short)rne16(v.x);
    Tsh[c * 4 + 1][t] = (unsigned short)rne16(v.y);
    Tsh[c * 4 + 2][t] = (unsigned short)rne16(v.z);
    Tsh[c * 4 + 3][t] = (unsigned short)rne16(v.w);
  }
  __syncthreads();
#pragma unroll
  for (int it = 0; it < 8; ++it) {
    const int idx = it * 256 + t;
    const int d = idx >> 5, c8 = (idx & 31) * 8;
    ushort8 v = *(const ushort8*)&Tsh[d][c8];
    *(ushort8*)(WT + (size_t)d * N_ROWS + blk * 256 + c8) = v;
  }
}

// One k-means iteration. 512 blocks x 256 threads (4 waves), 256 rows/block
// processed as 2 chunks of 128. Chunk-0 W loads issue at kernel top; chunk-1
// loads issue after chunk-0 phase1 frees the registers (T14, r12-verified).
// Phase 1: dot = mfma(Wrow-frag, C-frag) with RNE split precision.
// exp without max-sub (dist bounded); row sums via LDS column reads; attnT
// normalized in place. Phase 2: per-wave 32x32 quadrant of U = attnT @ W,
// B-frags from global WT (L3-hot); sumA denominator rides the same A-frags
// via a ones-B MFMA (idle matrix pipe, bit-consistent with numerator,
// r13-verified).
__global__ __launch_bounds__(256, 4) void dkm_iter(
    const float* __restrict__ W, const unsigned short* __restrict__ WT,
    const float* __restrict__ Cinit,
    const float* __restrict__ newC, float* __restrict__ cur,
    const double* __restrict__ normpart,
    float* __restrict__ partial, float* __restrict__ sumA,
    float* __restrict__ attn_out, int useSel, int writeAttn)
{
  __shared__ __align__(16) short CbfHi[64][68];   // clusters hi bf16 (pad 68)
  __shared__ __align__(16) short CbfLo[64][68];   // clusters lo bf16
  __shared__ __align__(16) short attnT[64][136];  // attn^T bf16 [cl][row], pad
  __shared__ float csqL[64];
  __shared__ float wsqL[128];                     // reused as invsL per chunk
  __shared__ int s_cond;

  const int t = threadIdx.x;
  const int blk = blockIdx.x;
  const int wid = t >> 6, lane = t & 63, l31 = lane & 31, lh = lane >> 5;
  const int mg = wid >> 1, ng = wid & 1;
  const int rowBase = blk * ROWS_PB;

  // ---- issue chunk-0 W row loads FIRST (latency hides under prologue) ----
  const float* pwBase = W + (size_t)(rowBase + wid * 32 + l31) * 64 + lh * 8;
  float4 vv[8];
#pragma unroll
  for (int q = 0; q < 8; ++q)
    vv[q] = *(const float4*)(pwBase + (q >> 1) * 16 + (q & 1) * 4);

  // ---- previous-iteration convergence gate (wave 0; 512 norm partials) ----
  if (wid == 0) {
    double v = 0.0;
    if (useSel) {
#pragma unroll
      for (int i = 0; i < 8; ++i) v += normpart[lane + 64 * i];
    }
    v += __shfl_xor(v, 1); v += __shfl_xor(v, 2); v += __shfl_xor(v, 4);
    v += __shfl_xor(v, 8); v += __shfl_xor(v, 16); v += __shfl_xor(v, 32);
    if (lane == 0) s_cond = (v > 1.0e-8) ? 1 : 0;  // ||.||_F > 1e-4
  }
  __syncthreads();  // s_cond ready

  const float* src = useSel ? (s_cond ? newC : cur) : Cinit;

  // ---- stage clusters (RNE split hi/lo), csq via 4-lane shfl, cur write ----
  {
    const int crow = t >> 2, cc = (t & 3) * 16;
    float sq = 0.f;
#pragma unroll
    for (int q = 0; q < 4; ++q) {
      float4 c0 = *(const float4*)(src + crow * 64 + cc + q * 4);
      if (blk == 0) *(float4*)(cur + crow * 64 + cc + q * 4) = c0;
      uint32_t h0, h1, l0, l1;
      split2(c0.x, c0.y, h0, l0);
      split2(c0.z, c0.w, h1, l1);
      uint32_t* ph = (uint32_t*)&CbfHi[crow][cc + q * 4];
      ph[0] = h0; ph[1] = h1;
      uint32_t* pl = (uint32_t*)&CbfLo[crow][cc + q * 4];
      pl[0] = l0; pl[1] = l1;
      sq += c0.x*c0.x + c0.y*c0.y + c0.z*c0.z + c0.w*c0.w;
    }
    sq += __shfl_xor(sq, 1);
    sq += __shfl_xor(sq, 2);
    if ((t & 3) == 0) csqL[crow] = sq;
  }
  __syncthreads();  // CbfHi/CbfLo + csqL ready

  float16 Uacc = {0,0,0,0, 0,0,0,0, 0,0,0,0, 0,0,0,0};
  float16 Uacc1 = {0,0,0,0, 0,0,0,0, 0,0,0,0, 0,0,0,0};
  const short8 ones = {0x3F80, 0x3F80, 0x3F80, 0x3F80,
                       0x3F80, 0x3F80, 0x3F80, 0x3F80};  // bf16 1.0 x8
  const float cq0 = csqL[l31], cq1 = csqL[32 + l31];

#pragma unroll
  for (int c = 0; c < 2; ++c) {
    const int chunkBase = rowBase + c * 128;

    // ---- phase 1: dot = mfma(Wrow-frag, C-frag), fused split+MFMA ----
    float16 dot0 = {0,0,0,0, 0,0,0,0, 0,0,0,0, 0,0,0,0};
    float16 dot1 = {0,0,0,0, 0,0,0,0, 0,0,0,0, 0,0,0,0};
    float w2acc = 0.f;
#pragma unroll
    for (int ko = 0; ko < 4; ++ko) {
      float4 a = vv[ko * 2];
      float4 b = vv[ko * 2 + 1];
      w2acc += a.x*a.x + a.y*a.y + a.z*a.z + a.w*a.w
             + b.x*b.x + b.y*b.y + b.z*b.z + b.w*b.w;
      uint32_t h0, h1, h2, h3, l0, l1, l2, l3;
      split2(a.x, a.y, h0, l0); split2(a.z, a.w, h1, l1);
      split2(b.x, b.y, h2, l2); split2(b.z, b.w, h3, l3);
      uint4v th = {h0, h1, h2, h3};
      uint4v tl = {l0, l1, l2, l3};
      short8 aHi = __builtin_bit_cast(short8, th);
      short8 aLo = __builtin_bit_cast(short8, tl);
#pragma unroll
      for (int nt = 0; nt < 2; ++nt) {
        const unsigned long long* ph = (const unsigned long long*)&CbfHi[nt * 32 + l31][ko * 16 + lh * 8];
        const unsigned long long* pl = (const unsigned long long*)&CbfLo[nt * 32 + l31][ko * 16 + lh * 8];
        ulong2v vh = {ph[0], ph[1]};
        ulong2v vl = {pl[0], pl[1]};
        short8 cHi = __builtin_bit_cast(short8, vh);
        short8 cLo = __builtin_bit_cast(short8, vl);
        float16& dd = nt ? dot1 : dot0;
        dd = __builtin_amdgcn_mfma_f32_32x32x16_bf16(aHi, cHi, dd, 0, 0, 0);
        dd = __builtin_amdgcn_mfma_f32_32x32x16_bf16(aLo, cHi, dd, 0, 0, 0);
        dd = __builtin_amdgcn_mfma_f32_32x32x16_bf16(aHi, cLo, dd, 0, 0, 0);
      }
    }
    w2acc += __shfl_xor(w2acc, 32);
    if (lane < 32) wsqL[wid * 32 + l31] = w2acc;

    // ---- prefetch next chunk's W rows (vv dead after phase1) ----
    if (c == 0) {
      const float* pwN = pwBase + 128 * 64;
#pragma unroll
      for (int q = 0; q < 8; ++q)
        vv[q] = *(const float4*)(pwN + (q >> 1) * 16 + (q & 1) * 4);
    }

    // ---- scores -> e = exp(-dist); no max-sub, no cross-lane ----
#pragma unroll
    for (int j = 0; j < 16; ++j) {
      const int trow = (j & 3) + 8 * (j >> 2) + 4 * lh;
      const float w2 = wsqL[wid * 32 + trow];  // own-wave LDS, in-order
      float g0 = -sqrtf(fmaxf(fmaf(-2.f, dot0[j], w2 + cq0), 0.f));
      float g1 = -sqrtf(fmaxf(fmaf(-2.f, dot1[j], w2 + cq1), 0.f));
      dot0[j] = __expf(g0);
      dot1[j] = __expf(g1);
    }

    // ---- iter 9 only: f32-accurate row sums for attn output ----
    if (writeAttn) {
#pragma unroll
      for (int j = 0; j < 16; ++j) {
        const int trow = (j & 3) + 8 * (j >> 2) + 4 * lh;
        float sj = dot0[j] + dot1[j];
        sj += __shfl_xor(sj, 1);  sj += __shfl_xor(sj, 2);  sj += __shfl_xor(sj, 4);
        sj += __shfl_xor(sj, 8);  sj += __shfl_xor(sj, 16);
        float inv = __builtin_amdgcn_rcpf(sj);
        attn_out[(size_t)(chunkBase + wid * 32 + trow) * 64 + l31] = dot0[j] * inv;
        attn_out[(size_t)(chunkBase + wid * 32 + trow) * 64 + 32 + l31] = dot1[j] * inv;
      }
    }

    // ---- attnT pack: UNNORMALIZED bf16(e), transposed [cl][row] ----
    {
      uint32_t* aT = (uint32_t*)&attnT[0][0];  // row stride 68 dwords
      const int cb = wid * 16;
#pragma unroll
      for (int h = 0; h < 4; ++h) {
        const int base = cb + 4 * h + 2 * lh;  // rows 8h+4lh+(0..3)
        aT[l31 * 68 + base]     = pack_bf16(dot0[4 * h],     dot0[4 * h + 1]);
        aT[l31 * 68 + base + 1] = pack_bf16(dot0[4 * h + 2], dot0[4 * h + 3]);
        aT[(32 + l31) * 68 + base]     = pack_bf16(dot1[4 * h],     dot1[4 * h + 1]);
        aT[(32 + l31) * 68 + base + 1] = pack_bf16(dot1[4 * h + 2], dot1[4 * h + 3]);
      }
    }
    __syncthreads();  // attnT(e) complete; wsqL dead -> invsL

    // ---- row sums of bf16(e) via attnT column reads -> invsL[r] ----
    float* invsL = wsqL;
    {
      const int r = t >> 1, kh = t & 1;
      float s = 0.f;
#pragma unroll
      for (int kk = 0; kk < 32; ++kk) {
        uint32_t v = (uint32_t)(unsigned short)attnT[kh * 32 + kk][r];
        s += __uint_as_float(v << 16);
      }
      s += __shfl_xor(s, 1);
      if (kh == 0) invsL[r] = __builtin_amdgcn_rcpf(s);
    }
    __syncthreads();  // invsL ready

    // ---- normalize attnT in place (bank-derotated RMW order) ----
    {
      const int k = t >> 2, q = t & 3;
      uint32_t* row = (uint32_t*)&attnT[k][0];
#pragma unroll
      for (int i = 0; i < 16; ++i) {
        const int ii = (i + k) & 15;
        const int r2 = q * 32 + 2 * ii;
        uint32_t dv = row[q * 16 + ii];
        float lo = __uint_as_float(dv << 16) * invsL[r2];
        float hi = __uint_as_float(dv & 0xffff0000u) * invsL[r2 + 1];
        row[q * 16 + ii] = pack_bf16(lo, hi);
      }
    }
    __syncthreads();  // attnT normalized

    // ---- phase 2: U-quadrant (mg,ng) over this chunk's K=128;
    //      B from global WT (L3-hot); sumA rides ones-MFMA ----
    const unsigned short* pwt =
        WT + (size_t)(ng * 32 + l31) * N_ROWS + chunkBase + lh * 8;
#pragma unroll
    for (int kc = 0; kc < 8; ++kc) {
      const unsigned long long* pa =
          (const unsigned long long*)&attnT[mg * 32 + l31][kc * 16 + lh * 8];
      ulong2v va = {pa[0], pa[1]};
      short8 af = __builtin_bit_cast(short8, va);
      ushort8 wv = *(const ushort8*)(pwt + kc * 16);
      short8 bf = __builtin_bit_cast(short8, wv);
      Uacc = __builtin_amdgcn_mfma_f32_32x32x16_bf16(af, bf, Uacc, 0, 0, 0);
      Uacc1 = __builtin_amdgcn_mfma_f32_32x32x16_bf16(af, ones, Uacc1, 0, 0, 0);
    }
    __syncthreads();  // chunk done: attnT/wsqL reusable next chunk
  }

  // ---- per-block partial + sumA (denominator = ones-MFMA columns) ----
#pragma unroll
  for (int j = 0; j < 16; ++j) {
    const int k = mg * 32 + (j & 3) + 8 * (j >> 2) + 4 * lh;
    partial[((size_t)blk * 64 + k) * 64 + ng * 32 + l31] = Uacc[j];
  }
  if (ng == 0 && l31 == 0) {
#pragma unroll
    for (int j = 0; j < 16; ++j) {
      const int k = mg * 32 + (j & 3) + 8 * (j >> 2) + 4 * lh;
      sumA[blk * 64 + k] = Uacc1[j];
    }
  }
}

// Reduce 512 block partials -> newC (f64), norm partials.
// 512 blocks = (k, d-octant): 16-deep chains.
__global__ __launch_bounds__(256) void reduce_kernel(
    const float* __restrict__ partial, const float* __restrict__ sumAp,
    const float* __restrict__ curC, float* __restrict__ newC,
    double* __restrict__ normpart) {
  const int k = blockIdx.x >> 3, oct = blockIdx.x & 7;
  const int t = threadIdx.x;
  const int d = oct * 8 + (t & 7), q = t >> 3;  // 32 q-groups of 8 threads
  double acc = 0.0;
  for (int b = q * 16; b < q * 16 + 16; ++b)
    acc += (double)partial[((size_t)b * 64 + k) * 64 + d];
  __shared__ double sh[256];
  __shared__ double sh2[256];
  sh[t] = acc;
  sh2[t] = (double)sumAp[t * 64 + k] + (double)sumAp[(t + 256) * 64 + k];
  __syncthreads();
#pragma unroll
  for (int s = 128; s >= 8; s >>= 1) {  // strides >=8 preserve t&7 lanes
    if (t < s) { sh[t] += sh[t + s]; sh2[t] += sh2[t + s]; }
    __syncthreads();
  }
#pragma unroll
  for (int s = 4; s >= 1; s >>= 1) {    // finish denominator tree only
    if (t < s) sh2[t] += sh2[t + s];
    __syncthreads();
  }
  if (t < 8) {
    float nc = (float)(sh[t] / sh2[0]);
    newC[k * 64 + d] = nc;
    double diff = (double)curC[k * 64 + d] - (double)nc;
    sh[t] = diff * diff;
  }
  __syncthreads();
  if (t == 0) {
    double s = 0.0;
#pragma unroll
    for (int i = 0; i < 8; ++i) s += sh[i];
    normpart[blockIdx.x] = s;
  }
}

// Final select: clusters_out = (||cur9 - new9|| > eps) ? newC : cur
// (cur aliases clusters_out; per-element read-then-write is safe)
__global__ __launch_bounds__(256) void finalize_kernel(
    const double* __restrict__ np, const float* __restrict__ newC,
    const float* __restrict__ cur, float* __restrict__ clusters_out) {
  __shared__ double sh[64];
  __shared__ int sc;
  int t = threadIdx.x;
  if (t < 64) {
    double v = 0.0;
#pragma unroll
    for (int i = 0; i < 8; ++i) v += np[t + 64 * i];
    sh[t] = v;
  }
  __syncthreads();
  if (t == 0) {
    double s = 0.0;
    for (int i = 0; i < 64; ++i) s += sh[i];
    sc = (s > 1.0e-8) ? 1 : 0;
  }
  __syncthreads();
  const float* src = sc ? newC : cur;
  for (int m = t; m < 4096; m += 256) {
    float v = src[m];
    clusters_out[m] = v;
  }
}

// compressed = attn @ clusters  (exact f32; reads only attn_out/clusters_out)
__global__ __launch_bounds__(256) void compress_kernel(
    const float* __restrict__ attn, const float* __restrict__ Cl,
    float* __restrict__ outC) {
  __shared__ float Csh[64 * 64];
  __shared__ float Ash[64 * 64];
  float4* Csh4 = (float4*)Csh;
  float4* Ash4 = (float4*)Ash;
  const int t = threadIdx.x;
  const int blk = blockIdx.x;
  const int rowBase = blk * 256;
  const int rg = t >> 4, dg = t & 15;

  {
    const float4* gC = (const float4*)Cl;
#pragma unroll
    for (int q = 0; q < 4; ++q) {
      int m = t + 256 * q;
      Csh4[m ^ ((m >> 6) & 15)] = gC[m];
    }
  }

  for (int tile = 0; tile < 4; ++tile) {
    __syncthreads();
    {
      const float4* gA = (const float4*)(attn + (size_t)(rowBase + tile * 64) * KC);
#pragma unroll
      for (int q = 0; q < 4; ++q) {
        int m = t + 256 * q;
        Ash4[m ^ ((m >> 6) & 15)] = gA[m];
      }
    }
    __syncthreads();
    float acc[4][4] = {{0.f}};
#pragma unroll 4
    for (int c = 0; c < 16; ++c) {
      float4 av[4], cv[4];
#pragma unroll
      for (int i = 0; i < 4; ++i) av[i] = Ash4[((rg * 4 + i) * 16 + c) ^ rg];
#pragma unroll
      for (int j = 0; j < 4; ++j) cv[j] = Csh4[((c * 4 + j) * 16 + dg) ^ c];
#pragma unroll
      for (int i = 0; i < 4; ++i) {
        float a0 = fmaf(av[i].x, cv[0].x, acc[i][0]);
        a0 = fmaf(av[i].y, cv[1].x, a0);
        a0 = fmaf(av[i].z, cv[2].x, a0);
        acc[i][0] = fmaf(av[i].w, cv[3].x, a0);
        float a1 = fmaf(av[i].x, cv[0].y, acc[i][1]);
        a1 = fmaf(av[i].y, cv[1].y, a1);
        a1 = fmaf(av[i].z, cv[2].y, a1);
        acc[i][1] = fmaf(av[i].w, cv[3].y, a1);
        float a2 = fmaf(av[i].x, cv[0].z, acc[i][2]);
        a2 = fmaf(av[i].y, cv[1].z, a2);
        a2 = fmaf(av[i].z, cv[2].z, a2);
        acc[i][2] = fmaf(av[i].w, cv[3].z, a2);
        float a3 = fmaf(av[i].x, cv[0].w, acc[i][3]);
        a3 = fmaf(av[i].y, cv[1].w, a3);
        a3 = fmaf(av[i].z, cv[2].w, a3);
        acc[i][3] = fmaf(av[i].w, cv[3].w, a3);
      }
    }
    float4* gO = (float4*)(outC + (size_t)(rowBase + tile * 64) * DIM);
#pragma unroll
    for (int i = 0; i < 4; ++i)
      gO[(rg * 4 + i) * 16 + dg] = make_float4(acc[i][0], acc[i][1], acc[i][2], acc[i][3]);
  }
}

extern "C" void kernel_launch(void* const* d_in, const int* in_sizes, int n_in,
                              void* d_out, int out_size, void* d_ws, size_t ws_size,
                              hipStream_t stream) {
  (void)in_sizes; (void)n_in; (void)d_ws; (void)ws_size; (void)out_size;
  const float* W = (const float*)d_in[0];
  const float* Cinit = (const float*)d_in[1];
  float* ob = (float*)d_out;

  float* compressed = ob;                                  // [N, D]
  float* clusters_out = ob + (size_t)N_ROWS * DIM;         // [K, D]
  float* attn_out = ob + (size_t)N_ROWS * DIM + KC * DIM;  // [N, K]

  unsigned short* WT = (unsigned short*)d_out;             // 16.7MB at byte 0
  float* partial = ob + PARTIAL_OFF;
  float* sumAp = ob + SUMA_OFF;
  float* newC = ob + NEWC_OFF;
  float* cur = clusters_out;                               // 16KB exact
  double* normpart = (double*)((char*)d_out + NORM_BYTE_OFF);

  prep_kernel<<<NBLK, 256, 0, stream>>>(W, WT);

  for (int it = 0; it < 10; ++it) {
    dkm_iter<<<NBLK, 256, 0, stream>>>(W, WT, Cinit, newC, cur, normpart,
                                       partial, sumAp, attn_out,
                                       (it > 0) ? 1 : 0, (it == 9) ? 1 : 0);
    reduce_kernel<<<512, 256, 0, stream>>>(partial, sumAp, cur, newC, normpart);
  }
  finalize_kernel<<<1, 256, 0, stream>>>(normpart, newC, cur, clusters_out);
  compress_kernel<<<512, 256, 0, stream>>>(attn_out, clusters_out, compressed);
}

// Round 15
// 339.672 us; speedup vs baseline: 1.2255x; 1.2255x over previous
//
#include <hip/hip_runtime.h>
#include <math.h>
#include <stdint.h>

#define N_ROWS 131072
#define DIM 64
#define KC 64
#define NBLK 512
#define ROWS_PB 256

typedef __attribute__((ext_vector_type(8))) short short8;
typedef __attribute__((ext_vector_type(8))) unsigned short ushort8;
typedef __attribute__((ext_vector_type(16))) float float16;
typedef __attribute__((ext_vector_type(2))) unsigned long long ulong2v;

// scratch layout (float offsets into d_out's compressed region [0, 8388608)):
// partial [512][64][64] f32 = 8.4MB at 0; sumA [512][64]; wsq [131072];
// newC [64][64]; normpart 512 doubles. cur aliases clusters_out.
// WS (pre-split W: per row 64 hi-bf16 + 64 lo-bf16 = 256B) lives IN the
// attn region: WS row n and attn row n are the same bytes; blocks read only
// their own rows' WS before their own iter-9 attn writes (per-thread program
// order, disjoint rows across blocks), and prep rebuilds WS each launch.
#define PARTIAL_OFF 0u
#define SUMA_OFF    2097152u
#define WSQ_OFF     2129920u
#define NEWC_OFF    2260992u
#define NORM_BYTE_OFF (2265088ull * 4ull)

// round-to-nearest-even bf16 (unbiased; truncation measured 7e-4 cluster err)
__device__ __forceinline__ uint32_t rne16(float a) {
  uint32_t u = __float_as_uint(a);
  return (u + 0x7fffu + ((u >> 16) & 1u)) >> 16;
}

__device__ __forceinline__ uint32_t pack_bf16(float a, float b) {
  return rne16(a) | (rne16(b) << 16);
}

// RNE split: x = hi + lo + eps, |lo| <= 2^-9|x|, |eps| <= 2^-17|x|, unbiased
__device__ __forceinline__ void split2(float a, float b, uint32_t& hi, uint32_t& lo) {
  uint32_t ha = rne16(a), hb = rne16(b);
  hi = ha | (hb << 16);
  float la = a - __uint_as_float(ha << 16);
  float lb = b - __uint_as_float(hb << 16);
  lo = pack_bf16(la, lb);
}

// prep: WS[r] = {hi bf16[64], lo bf16[64]} (RNE split of W row, done ONCE --
// r12 re-split W every iteration: ~400 VALU ops/thread/iter) + wsq[r].
__global__ __launch_bounds__(256) void prep_kernel(const float* __restrict__ W,
                                                   unsigned short* WS,
                                                   float* __restrict__ wsq) {
  const int t = threadIdx.x;
  const int r = blockIdx.x * 256 + t;
  const float4* p = (const float4*)(W + (size_t)r * DIM);
  uint32_t* hi = (uint32_t*)(WS + (size_t)r * 128);
  uint32_t* lo = hi + 32;
  float s = 0.f;
#pragma unroll
  for (int c = 0; c < 16; ++c) {
    float4 v = p[c];
    s += v.x * v.x + v.y * v.y + v.z * v.z + v.w * v.w;
    uint32_t h0, h1, l0, l1;
    split2(v.x, v.y, h0, l0);
    split2(v.z, v.w, h1, l1);
    hi[c * 2] = h0; hi[c * 2 + 1] = h1;
    lo[c * 2] = l0; lo[c * 2 + 1] = l1;
  }
  wsq[r] = s;
}

// One k-means iteration. 512 blocks x 256 threads (4 waves), 256 rows/block
// processed as 2 chunks of 128 (r12 structure, 355us verified-best).
// Phase 1: dot = mfma(Wrow-frag, C-frag), A-frags loaded pre-split from WS
// (bit-identical to r12's in-kernel split); chunk-1 frags prefetched after
// chunk-0 phase1 (T14). exp without max-sub; row sums via LDS column reads;
// attnT normalized in place. Phase 2: per-wave 32x32 quadrant of
// U = attnT @ W over K=128 (B from WTsh LDS); the sumA denominator rides
// the same A-frags via a ones-B MFMA (r13 bit-exact-verified).
__global__ __launch_bounds__(256, 3) void dkm_iter(
    const unsigned short* WS, const float* __restrict__ wsq,
    const float* __restrict__ Cinit,
    const float* __restrict__ newC, float* __restrict__ cur,
    const double* __restrict__ normpart,
    float* __restrict__ partial, float* __restrict__ sumA,
    float* attn_out, int useSel, int writeAttn)
{
  __shared__ __align__(16) short CbfHi[64][68];   // clusters hi bf16 (pad 68)
  __shared__ __align__(16) short CbfLo[64][68];   // clusters lo bf16
  __shared__ __align__(16) short attnT[64][136];  // attn^T bf16 [cl][row], pad
  __shared__ __align__(16) short WTsh[64][136];   // W^T bf16 [dim][row], pad
  __shared__ float csqL[64];
  __shared__ float wsqL[128];                     // reused as invsL per chunk
  __shared__ int s_cond;

  const int t = threadIdx.x;
  const int blk = blockIdx.x;
  const int wid = t >> 6, lane = t & 63, l31 = lane & 31, lh = lane >> 5;
  const int mg = wid >> 1, ng = wid & 1;
  const int rowBase = blk * ROWS_PB;
  const int colA = wid * 32 + l31;

  // ---- issue chunk-0 WS frag loads FIRST (hide under prologue) ----
  const unsigned short* pws =
      WS + (size_t)(rowBase + wid * 32 + l31) * 128 + lh * 8;
  ushort8 vh[4], vl[4];
#pragma unroll
  for (int ko = 0; ko < 4; ++ko) {
    vh[ko] = *(const ushort8*)(pws + ko * 16);
    vl[ko] = *(const ushort8*)(pws + 64 + ko * 16);
  }

  // ---- previous-iteration convergence gate (wave 0; 512 norm partials) ----
  if (wid == 0) {
    double v = 0.0;
    if (useSel) {
#pragma unroll
      for (int i = 0; i < 8; ++i) v += normpart[lane + 64 * i];
    }
    v += __shfl_xor(v, 1); v += __shfl_xor(v, 2); v += __shfl_xor(v, 4);
    v += __shfl_xor(v, 8); v += __shfl_xor(v, 16); v += __shfl_xor(v, 32);
    if (lane == 0) s_cond = (v > 1.0e-8) ? 1 : 0;  // ||.||_F > 1e-4
  }
  __syncthreads();  // s_cond ready

  const float* src = useSel ? (s_cond ? newC : cur) : Cinit;

  // ---- stage clusters (RNE split hi/lo), csq via 4-lane shfl, cur write ----
  {
    const int crow = t >> 2, cc = (t & 3) * 16;
    float sq = 0.f;
#pragma unroll
    for (int q = 0; q < 4; ++q) {
      float4 c0 = *(const float4*)(src + crow * 64 + cc + q * 4);
      if (blk == 0) *(float4*)(cur + crow * 64 + cc + q * 4) = c0;
      uint32_t h0, h1, l0, l1;
      split2(c0.x, c0.y, h0, l0);
      split2(c0.z, c0.w, h1, l1);
      uint32_t* ph = (uint32_t*)&CbfHi[crow][cc + q * 4];
      ph[0] = h0; ph[1] = h1;
      uint32_t* pl = (uint32_t*)&CbfLo[crow][cc + q * 4];
      pl[0] = l0; pl[1] = l1;
      sq += c0.x*c0.x + c0.y*c0.y + c0.z*c0.z + c0.w*c0.w;
    }
    sq += __shfl_xor(sq, 1);
    sq += __shfl_xor(sq, 2);
    if ((t & 3) == 0) csqL[crow] = sq;
  }
  __syncthreads();  // CbfHi/CbfLo + csqL ready

  float16 Uacc = {0,0,0,0, 0,0,0,0, 0,0,0,0, 0,0,0,0};
  float16 Uacc1 = {0,0,0,0, 0,0,0,0, 0,0,0,0, 0,0,0,0};
  const short8 ones = {0x3F80, 0x3F80, 0x3F80, 0x3F80,
                       0x3F80, 0x3F80, 0x3F80, 0x3F80};  // bf16 1.0 x8
  const float cq0 = csqL[l31], cq1 = csqL[32 + l31];

#pragma unroll
  for (int c = 0; c < 2; ++c) {
    const int chunkBase = rowBase + c * 128;

    if (t < 128) wsqL[t] = wsq[chunkBase + t];

    // ---- phase 1: dot = mfma(Wrow-frag, C-frag); deposit hi->WTsh ----
    float16 dot0 = {0,0,0,0, 0,0,0,0, 0,0,0,0, 0,0,0,0};
    float16 dot1 = {0,0,0,0, 0,0,0,0, 0,0,0,0, 0,0,0,0};
#pragma unroll
    for (int ko = 0; ko < 4; ++ko) {
      const int d0 = ko * 16 + lh * 8;
      WTsh[d0 + 0][colA] = vh[ko][0];  WTsh[d0 + 1][colA] = vh[ko][1];
      WTsh[d0 + 2][colA] = vh[ko][2];  WTsh[d0 + 3][colA] = vh[ko][3];
      WTsh[d0 + 4][colA] = vh[ko][4];  WTsh[d0 + 5][colA] = vh[ko][5];
      WTsh[d0 + 6][colA] = vh[ko][6];  WTsh[d0 + 7][colA] = vh[ko][7];
      short8 aHi = __builtin_bit_cast(short8, vh[ko]);
      short8 aLo = __builtin_bit_cast(short8, vl[ko]);
#pragma unroll
      for (int nt = 0; nt < 2; ++nt) {
        const unsigned long long* ph = (const unsigned long long*)&CbfHi[nt * 32 + l31][ko * 16 + lh * 8];
        const unsigned long long* pl = (const unsigned long long*)&CbfLo[nt * 32 + l31][ko * 16 + lh * 8];
        ulong2v vhh = {ph[0], ph[1]};
        ulong2v vll = {pl[0], pl[1]};
        short8 cHi = __builtin_bit_cast(short8, vhh);
        short8 cLo = __builtin_bit_cast(short8, vll);
        float16& dd = nt ? dot1 : dot0;
        dd = __builtin_amdgcn_mfma_f32_32x32x16_bf16(aHi, cHi, dd, 0, 0, 0);
        dd = __builtin_amdgcn_mfma_f32_32x32x16_bf16(aLo, cHi, dd, 0, 0, 0);
        dd = __builtin_amdgcn_mfma_f32_32x32x16_bf16(aHi, cLo, dd, 0, 0, 0);
      }
    }

    // ---- prefetch next chunk's WS frags (vh/vl dead after phase1) ----
    if (c == 0) {
      const unsigned short* pwN = pws + 128 * 128;
#pragma unroll
      for (int ko = 0; ko < 4; ++ko) {
        vh[ko] = *(const ushort8*)(pwN + ko * 16);
        vl[ko] = *(const ushort8*)(pwN + 64 + ko * 16);
      }
    }

    // ---- scores -> e = exp(-dist); no max-sub, no cross-lane ----
#pragma unroll
    for (int j = 0; j < 16; ++j) {
      const int trow = (j & 3) + 8 * (j >> 2) + 4 * lh;
      const float w2 = wsqL[wid * 32 + trow];  // own-wave LDS, in-order
      float g0 = -sqrtf(fmaxf(fmaf(-2.f, dot0[j], w2 + cq0), 0.f));
      float g1 = -sqrtf(fmaxf(fmaf(-2.f, dot1[j], w2 + cq1), 0.f));
      dot0[j] = __expf(g0);
      dot1[j] = __expf(g1);
    }

    // ---- iter 9 only: f32-accurate row sums for attn output.
    //      attn row n aliases WS row n: this thread's WS reads for both
    //      chunks already happened (top + prefetch above) ----
    if (writeAttn) {
#pragma unroll
      for (int j = 0; j < 16; ++j) {
        const int trow = (j & 3) + 8 * (j >> 2) + 4 * lh;
        float sj = dot0[j] + dot1[j];
        sj += __shfl_xor(sj, 1);  sj += __shfl_xor(sj, 2);  sj += __shfl_xor(sj, 4);
        sj += __shfl_xor(sj, 8);  sj += __shfl_xor(sj, 16);
        float inv = __builtin_amdgcn_rcpf(sj);
        attn_out[(size_t)(chunkBase + wid * 32 + trow) * 64 + l31] = dot0[j] * inv;
        attn_out[(size_t)(chunkBase + wid * 32 + trow) * 64 + 32 + l31] = dot1[j] * inv;
      }
    }

    // ---- attnT pack: UNNORMALIZED bf16(e), transposed [cl][row] ----
    {
      uint32_t* aT = (uint32_t*)&attnT[0][0];  // row stride 68 dwords
      const int cb = wid * 16;
#pragma unroll
      for (int h = 0; h < 4; ++h) {
        const int base = cb + 4 * h + 2 * lh;  // rows 8h+4lh+(0..3)
        aT[l31 * 68 + base]     = pack_bf16(dot0[4 * h],     dot0[4 * h + 1]);
        aT[l31 * 68 + base + 1] = pack_bf16(dot0[4 * h + 2], dot0[4 * h + 3]);
        aT[(32 + l31) * 68 + base]     = pack_bf16(dot1[4 * h],     dot1[4 * h + 1]);
        aT[(32 + l31) * 68 + base + 1] = pack_bf16(dot1[4 * h + 2], dot1[4 * h + 3]);
      }
    }
    __syncthreads();  // attnT(e) + WTsh complete; wsqL dead -> invsL

    // ---- row sums of bf16(e) via attnT column reads -> invsL[r] ----
    float* invsL = wsqL;
    {
      const int r = t >> 1, kh = t & 1;
      float s = 0.f;
#pragma unroll
      for (int kk = 0; kk < 32; ++kk) {
        uint32_t v = (uint32_t)(unsigned short)attnT[kh * 32 + kk][r];
        s += __uint_as_float(v << 16);
      }
      s += __shfl_xor(s, 1);
      if (kh == 0) invsL[r] = __builtin_amdgcn_rcpf(s);
    }
    __syncthreads();  // invsL ready

    // ---- normalize attnT in place (bank-derotated RMW order) ----
    {
      const int k = t >> 2, q = t & 3;
      uint32_t* row = (uint32_t*)&attnT[k][0];
#pragma unroll
      for (int i = 0; i < 16; ++i) {
        const int ii = (i + k) & 15;
        const int r2 = q * 32 + 2 * ii;
        uint32_t dv = row[q * 16 + ii];
        float lo = __uint_as_float(dv << 16) * invsL[r2];
        float hi = __uint_as_float(dv & 0xffff0000u) * invsL[r2 + 1];
        row[q * 16 + ii] = pack_bf16(lo, hi);
      }
    }
    __syncthreads();  // attnT normalized

    // ---- phase 2: U-quadrant (mg,ng); sumA rides ones-MFMA ----
#pragma unroll
    for (int kc = 0; kc < 8; ++kc) {
      const unsigned long long* pa =
          (const unsigned long long*)&attnT[mg * 32 + l31][kc * 16 + lh * 8];
      ulong2v va = {pa[0], pa[1]};
      short8 af = __builtin_bit_cast(short8, va);
      const unsigned long long* pb =
          (const unsigned long long*)&WTsh[ng * 32 + l31][kc * 16 + lh * 8];
      ulong2v vb = {pb[0], pb[1]};
      short8 bf = __builtin_bit_cast(short8, vb);
      Uacc = __builtin_amdgcn_mfma_f32_32x32x16_bf16(af, bf, Uacc, 0, 0, 0);
      Uacc1 = __builtin_amdgcn_mfma_f32_32x32x16_bf16(af, ones, Uacc1, 0, 0, 0);
    }
    __syncthreads();  // chunk done: attnT/WTsh/wsqL reusable next chunk
  }

  // ---- per-block partial + sumA (denominator = ones-MFMA columns) ----
#pragma unroll
  for (int j = 0; j < 16; ++j) {
    const int k = mg * 32 + (j & 3) + 8 * (j >> 2) + 4 * lh;
    partial[((size_t)blk * 64 + k) * 64 + ng * 32 + l31] = Uacc[j];
  }
  if (ng == 0 && l31 == 0) {
#pragma unroll
    for (int j = 0; j < 16; ++j) {
      const int k = mg * 32 + (j & 3) + 8 * (j >> 2) + 4 * lh;
      sumA[blk * 64 + k] = Uacc1[j];
    }
  }
}

// Reduce 512 block partials -> newC (f64), norm partials.
// 512 blocks = (k, d-octant): 16-deep chains.
__global__ __launch_bounds__(256) void reduce_kernel(
    const float* __restrict__ partial, const float* __restrict__ sumAp,
    const float* __restrict__ curC, float* __restrict__ newC,
    double* __restrict__ normpart) {
  const int k = blockIdx.x >> 3, oct = blockIdx.x & 7;
  const int t = threadIdx.x;
  const int d = oct * 8 + (t & 7), q = t >> 3;  // 32 q-groups of 8 threads
  double acc = 0.0;
  for (int b = q * 16; b < q * 16 + 16; ++b)
    acc += (double)partial[((size_t)b * 64 + k) * 64 + d];
  __shared__ double sh[256];
  __shared__ double sh2[256];
  sh[t] = acc;
  sh2[t] = (double)sumAp[t * 64 + k] + (double)sumAp[(t + 256) * 64 + k];
  __syncthreads();
#pragma unroll
  for (int s = 128; s >= 8; s >>= 1) {  // strides >=8 preserve t&7 lanes
    if (t < s) { sh[t] += sh[t + s]; sh2[t] += sh2[t + s]; }
    __syncthreads();
  }
#pragma unroll
  for (int s = 4; s >= 1; s >>= 1) {    // finish denominator tree only
    if (t < s) sh2[t] += sh2[t + s];
    __syncthreads();
  }
  if (t < 8) {
    float nc = (float)(sh[t] / sh2[0]);
    newC[k * 64 + d] = nc;
    double diff = (double)curC[k * 64 + d] - (double)nc;
    sh[t] = diff * diff;
  }
  __syncthreads();
  if (t == 0) {
    double s = 0.0;
#pragma unroll
    for (int i = 0; i < 8; ++i) s += sh[i];
    normpart[blockIdx.x] = s;
  }
}

// Final select: clusters_out = (||cur9 - new9|| > eps) ? newC : cur
// (cur aliases clusters_out; per-element read-then-write is safe)
__global__ __launch_bounds__(256) void finalize_kernel(
    const double* __restrict__ np, const float* __restrict__ newC,
    const float* __restrict__ cur, float* __restrict__ clusters_out) {
  __shared__ double sh[64];
  __shared__ int sc;
  int t = threadIdx.x;
  if (t < 64) {
    double v = 0.0;
#pragma unroll
    for (int i = 0; i < 8; ++i) v += np[t + 64 * i];
    sh[t] = v;
  }
  __syncthreads();
  if (t == 0) {
    double s = 0.0;
    for (int i = 0; i < 64; ++i) s += sh[i];
    sc = (s > 1.0e-8) ? 1 : 0;
  }
  __syncthreads();
  const float* src = sc ? newC : cur;
  for (int m = t; m < 4096; m += 256) {
    float v = src[m];
    clusters_out[m] = v;
  }
}

// compressed = attn @ clusters  (exact f32; reads only attn_out/clusters_out)
__global__ __launch_bounds__(256) void compress_kernel(
    const float* __restrict__ attn, const float* __restrict__ Cl,
    float* __restrict__ outC) {
  __shared__ float Csh[64 * 64];
  __shared__ float Ash[64 * 64];
  float4* Csh4 = (float4*)Csh;
  float4* Ash4 = (float4*)Ash;
  const int t = threadIdx.x;
  const int blk = blockIdx.x;
  const int rowBase = blk * 256;
  const int rg = t >> 4, dg = t & 15;

  {
    const float4* gC = (const float4*)Cl;
#pragma unroll
    for (int q = 0; q < 4; ++q) {
      int m = t + 256 * q;
      Csh4[m ^ ((m >> 6) & 15)] = gC[m];
    }
  }

  for (int tile = 0; tile < 4; ++tile) {
    __syncthreads();
    {
      const float4* gA = (const float4*)(attn + (size_t)(rowBase + tile * 64) * KC);
#pragma unroll
      for (int q = 0; q < 4; ++q) {
        int m = t + 256 * q;
        Ash4[m ^ ((m >> 6) & 15)] = gA[m];
      }
    }
    __syncthreads();
    float acc[4][4] = {{0.f}};
#pragma unroll 4
    for (int c = 0; c < 16; ++c) {
      float4 av[4], cv[4];
#pragma unroll
      for (int i = 0; i < 4; ++i) av[i] = Ash4[((rg * 4 + i) * 16 + c) ^ rg];
#pragma unroll
      for (int j = 0; j < 4; ++j) cv[j] = Csh4[((c * 4 + j) * 16 + dg) ^ c];
#pragma unroll
      for (int i = 0; i < 4; ++i) {
        float a0 = fmaf(av[i].x, cv[0].x, acc[i][0]);
        a0 = fmaf(av[i].y, cv[1].x, a0);
        a0 = fmaf(av[i].z, cv[2].x, a0);
        acc[i][0] = fmaf(av[i].w, cv[3].x, a0);
        float a1 = fmaf(av[i].x, cv[0].y, acc[i][1]);
        a1 = fmaf(av[i].y, cv[1].y, a1);
        a1 = fmaf(av[i].z, cv[2].y, a1);
        acc[i][1] = fmaf(av[i].w, cv[3].y, a1);
        float a2 = fmaf(av[i].x, cv[0].z, acc[i][2]);
        a2 = fmaf(av[i].y, cv[1].z, a2);
        a2 = fmaf(av[i].z, cv[2].z, a2);
        acc[i][2] = fmaf(av[i].w, cv[3].z, a2);
        float a3 = fmaf(av[i].x, cv[0].w, acc[i][3]);
        a3 = fmaf(av[i].y, cv[1].w, a3);
        a3 = fmaf(av[i].z, cv[2].w, a3);
        acc[i][3] = fmaf(av[i].w, cv[3].w, a3);
      }
    }
    float4* gO = (float4*)(outC + (size_t)(rowBase + tile * 64) * DIM);
#pragma unroll
    for (int i = 0; i < 4; ++i)
      gO[(rg * 4 + i) * 16 + dg] = make_float4(acc[i][0], acc[i][1], acc[i][2], acc[i][3]);
  }
}

extern "C" void kernel_launch(void* const* d_in, const int* in_sizes, int n_in,
                              void* d_out, int out_size, void* d_ws, size_t ws_size,
                              hipStream_t stream) {
  (void)in_sizes; (void)n_in; (void)d_ws; (void)ws_size; (void)out_size;
  const float* W = (const float*)d_in[0];
  const float* Cinit = (const float*)d_in[1];
  float* ob = (float*)d_out;

  float* compressed = ob;                                  // [N, D]
  float* clusters_out = ob + (size_t)N_ROWS * DIM;         // [K, D]
  float* attn_out = ob + (size_t)N_ROWS * DIM + KC * DIM;  // [N, K]

  unsigned short* WS = (unsigned short*)attn_out;          // WS aliases attn
  float* partial = ob + PARTIAL_OFF;
  float* sumAp = ob + SUMA_OFF;
  float* wsq = ob + WSQ_OFF;
  float* newC = ob + NEWC_OFF;
  float* cur = clusters_out;                               // 16KB exact
  double* normpart = (double*)((char*)d_out + NORM_BYTE_OFF);

  prep_kernel<<<NBLK, 256, 0, stream>>>(W, WS, wsq);

  for (int it = 0; it < 10; ++it) {
    dkm_iter<<<NBLK, 256, 0, stream>>>(WS, wsq, Cinit, newC, cur, normpart,
                                       partial, sumAp, attn_out,
                                       (it > 0) ? 1 : 0, (it == 9) ? 1 : 0);
    reduce_kernel<<<512, 256, 0, stream>>>(partial, sumAp, cur, newC, normpart);
  }
  finalize_kernel<<<1, 256, 0, stream>>>(normpart, newC, cur, clusters_out);
  compress_kernel<<<512, 256, 0, stream>>>(attn_out, clusters_out, compressed);
}